// Round 15
// baseline (424.389 us; speedup 1.0000x reference)
//
#include <hip/hip_runtime.h>

#define B_    4
#define S_    4096
#define D_    2048
#define DQ_   512
#define DF_   8192
#define KSEL_ 512
#define M_    (B_ * S_)     // 16384
#define MS_   (B_ * KSEL_)  // 2048 selected rows

typedef __attribute__((ext_vector_type(8))) short bf16x8;
typedef __attribute__((ext_vector_type(4))) float f32x4;
typedef __attribute__((address_space(3))) void as3_void;
typedef const __attribute__((address_space(1))) void as1_cvoid;

__device__ __forceinline__ unsigned short f2bf(float f) {
    unsigned u = __float_as_uint(f);
    u += 0x7FFFu + ((u >> 16) & 1u);   // RNE
    return (unsigned short)(u >> 16);
}
__device__ __forceinline__ float bf2f(unsigned short h) {
    return __uint_as_float(((unsigned)h) << 16);
}

__device__ __forceinline__ void gload16(const void* g, void* l) {
    __builtin_amdgcn_global_load_lds((as1_cvoid*)g, (as3_void*)l, 16, 0, 0);
}

// ---------------- split x into bf16 hi/lo (out-copy moved into router) ----------
__global__ void split_kernel(const float* __restrict__ x,
                             unsigned short* __restrict__ xh,
                             unsigned short* __restrict__ xl, int n8) {
    int i = blockIdx.x * blockDim.x + threadIdx.x;
    int stride = gridDim.x * blockDim.x;
    for (; i < n8; i += stride) {
        float4 a = ((const float4*)x)[2 * i];
        float4 b = ((const float4*)x)[2 * i + 1];
        float v[8] = {a.x, a.y, a.z, a.w, b.x, b.y, b.z, b.w};
        unsigned short hi[8], lo[8];
#pragma unroll
        for (int j = 0; j < 8; j++) {
            hi[j] = f2bf(v[j]);
            lo[j] = f2bf(v[j] - bf2f(hi[j]));
        }
        *(uint4*)(xh + (size_t)i * 8) = *(const uint4*)hi;
        *(uint4*)(xl + (size_t)i * 8) = *(const uint4*)lo;
    }
}

// ---------------- Wr1 -> whiT [DQ][D], wloT [DQ][D] (bf16, transposed) ----------
__global__ void wsplit_kernel(const float* __restrict__ W,
                              unsigned short* __restrict__ whiT,
                              unsigned short* __restrict__ wloT) {
    __shared__ float tile[32][33];
    int tx = threadIdx.x, ty = threadIdx.y;          // 32 x 8
    int n0 = blockIdx.x * 32, k0 = blockIdx.y * 32;
#pragma unroll
    for (int j = 0; j < 4; j++)
        tile[ty + j * 8][tx] = W[(size_t)(k0 + ty + j * 8) * DQ_ + n0 + tx];   // tile[k][n]
    __syncthreads();
#pragma unroll
    for (int j = 0; j < 4; j++) {
        float v = tile[tx][ty + j * 8];              // k = k0+tx, n = n0+ty+j*8
        unsigned short hi = f2bf(v);
        unsigned short lo = f2bf(v - bf2f(hi));
        size_t row = (size_t)(n0 + ty + j * 8) * D_;
        whiT[row + k0 + tx] = hi;
        wloT[row + k0 + tx] = lo;
    }
}

// ---------------- transpose + fp32->bf16 convert: out[c][r] = bf16(in[r][c]) ----
__global__ void transpose_bf16_kernel(const float* __restrict__ in,
                                      unsigned short* __restrict__ out,
                                      int R, int C) {
    __shared__ float tile[32][33];
    int tx = threadIdx.x, ty = threadIdx.y;       // 32 x 8
    int c0 = blockIdx.x * 32, r0 = blockIdx.y * 32;
#pragma unroll
    for (int j = 0; j < 4; j++)
        tile[ty + j * 8][tx] = in[(size_t)(r0 + ty + j * 8) * C + c0 + tx];
    __syncthreads();
#pragma unroll
    for (int j = 0; j < 4; j++)
        out[(size_t)(c0 + ty + j * 8) * R + r0 + tx] = f2bf(tile[tx][ty + j * 8]);
}

// ======== pipelined router: 128x128 tile, BK=32, 4 waves, 2 blocks/CU ==========
// R10 config + fused x->out copy (1 float4/thread/K-step, flat 256KB per block).
// Issue order pinned: copyload -> RSTAGE -> copystore, so the store's auto-wait
// is vmcnt(8) (keeps stage loads in flight). Top wait vmcnt(9) (= stage 8 +
// prior store 1); kt==0 vmcnt(8); kt==63 vmcnt(0).
#define RSTAGE(bufp, ktX) do {                                              \
    const size_t ko_ = (size_t)(ktX) * 32;                                  \
    char* laH_ = (char*)(&sA[bufp][0][0]) + w * 1024;                       \
    char* laL_ = (char*)(&sA[bufp][1][0]) + w * 1024;                       \
    char* lbH_ = (char*)(&sB[bufp][0][0]) + w * 1024;                       \
    char* lbL_ = (char*)(&sB[bufp][1][0]) + w * 1024;                       \
    gload16(gAh + ko_,            laH_);                                    \
    gload16(gAh + 64 * D_ + ko_,  laH_ + 4096);                             \
    gload16(gAl + ko_,            laL_);                                    \
    gload16(gAl + 64 * D_ + ko_,  laL_ + 4096);                             \
    gload16(gBh + ko_,            lbH_);                                    \
    gload16(gBh + 64 * D_ + ko_,  lbH_ + 4096);                             \
    gload16(gBl + ko_,            lbL_);                                    \
    gload16(gBl + 64 * D_ + ko_,  lbL_ + 4096);                             \
  } while (0)

__global__ __launch_bounds__(256) void router_mfma(const unsigned short* __restrict__ xh,
                                                   const unsigned short* __restrict__ xl,
                                                   const unsigned short* __restrict__ whiT,
                                                   const unsigned short* __restrict__ wloT,
                                                   const float* __restrict__ br1,
                                                   const float* __restrict__ Wr2,
                                                   float* __restrict__ pscore,
                                                   const float* __restrict__ xf,
                                                   float* __restrict__ outp) {
    __shared__ unsigned short sA[2][2][128 * 32];   // [buf][hi|lo] 8KB tiles
    __shared__ unsigned short sB[2][2][128 * 32];
    const int t = threadIdx.x;
    const int w = t >> 6, l = t & 63;               // 4 waves
    const int m0 = blockIdx.x * 128, n0 = blockIdx.y * 128;
    const int wr = w >> 1, wc = w & 1;              // 2 x 2 wave grid, 64x64 each

    f32x4 acc[4][4];
    const f32x4 zz = {0.f, 0.f, 0.f, 0.f};
#pragma unroll
    for (int m = 0; m < 4; m++)
#pragma unroll
        for (int n = 0; n < 4; n++) acc[m][n] = zz;

    const int srow = t >> 2;
    const int sch8 = (((t & 3) ^ ((t >> 3) & 3)) * 8);
    const unsigned short* gAh = xh + (size_t)(m0 + srow) * D_ + sch8;
    const unsigned short* gAl = xl + (size_t)(m0 + srow) * D_ + sch8;
    const unsigned short* gBh = whiT + (size_t)(n0 + srow) * D_ + sch8;
    const unsigned short* gBl = wloT + (size_t)(n0 + srow) * D_ + sch8;

    // fused-copy region: flat quarter of this m-stripe (256 KB), 1 float4/thr/iter
    const float4* cpysrc = (const float4*)(xf + (size_t)m0 * D_) +
                           (size_t)blockIdx.y * 16384 + t;
    float4* cpydst = (float4*)(outp + (size_t)m0 * D_) +
                     (size_t)blockIdx.y * 16384 + t;

    RSTAGE(0, 0);
    RSTAGE(1, 1);

    const int fro = ((l >> 4) ^ ((l >> 1) & 3)) * 8;   // swizzled read chunk
    const int arB = (wr * 64 + (l & 15)) * 32 + fro;   // frag base (f adds 512)
    const int brB = (wc * 64 + (l & 15)) * 32 + fro;

    for (int kt = 0; kt < 64; ++kt) {
        if (kt == 0)      { asm volatile("s_waitcnt vmcnt(8)" ::: "memory"); }
        else if (kt < 63) { asm volatile("s_waitcnt vmcnt(9)" ::: "memory"); }
        else              { asm volatile("s_waitcnt vmcnt(0)" ::: "memory"); }
        __builtin_amdgcn_s_barrier();
        __builtin_amdgcn_sched_barrier(0);
        const int cur = kt & 1;
        const unsigned short* LAh = &sA[cur][0][0];
        const unsigned short* LAl = &sA[cur][1][0];
        const unsigned short* LBh = &sB[cur][0][0];
        const unsigned short* LBl = &sB[cur][1][0];
        bf16x8 ah[4], al[4], bh[4], bl[4];
#pragma unroll
        for (int f = 0; f < 4; f++) ah[f] = *(const bf16x8*)(LAh + arB + f * 512);
#pragma unroll
        for (int f = 0; f < 4; f++) bh[f] = *(const bf16x8*)(LBh + brB + f * 512);
#pragma unroll
        for (int f = 0; f < 4; f++) bl[f] = *(const bf16x8*)(LBl + brB + f * 512);
#pragma unroll
        for (int f = 0; f < 4; f++) al[f] = *(const bf16x8*)(LAl + arB + f * 512);
        __builtin_amdgcn_s_setprio(1);
#pragma unroll
        for (int m = 0; m < 4; m++)
#pragma unroll
            for (int n = 0; n < 4; n++)
                acc[m][n] = __builtin_amdgcn_mfma_f32_16x16x32_bf16(ah[m], bh[n], acc[m][n], 0, 0, 0);
#pragma unroll
        for (int m = 0; m < 4; m++)
#pragma unroll
            for (int n = 0; n < 4; n++)
                acc[m][n] = __builtin_amdgcn_mfma_f32_16x16x32_bf16(ah[m], bl[n], acc[m][n], 0, 0, 0);
#pragma unroll
        for (int m = 0; m < 4; m++)
#pragma unroll
            for (int n = 0; n < 4; n++)
                acc[m][n] = __builtin_amdgcn_mfma_f32_16x16x32_bf16(al[m], bh[n], acc[m][n], 0, 0, 0);
        __builtin_amdgcn_s_setprio(0);
        __builtin_amdgcn_sched_barrier(0);
        __builtin_amdgcn_s_barrier();
        // fused copy: load first, then stage, then store (auto-wait = vmcnt(8))
        float4 cv = cpysrc[(size_t)kt * 256];
        __builtin_amdgcn_sched_barrier(0);
        if (kt + 2 < 64) RSTAGE(cur, kt + 2);
        __builtin_amdgcn_sched_barrier(0);
        cpydst[(size_t)kt * 256] = cv;
    }

    // epilogue: fused scores partial dot (relu(acc + br1) . Wr2 over 64-col slice)
    float br1v[4], wr2v[4];
#pragma unroll
    for (int nf = 0; nf < 4; nf++) {
        int col = n0 + wc * 64 + nf * 16 + (l & 15);
        br1v[nf] = br1[col];
        wr2v[nf] = Wr2[col];
    }
#pragma unroll
    for (int mf = 0; mf < 4; mf++)
#pragma unroll
        for (int q = 0; q < 4; q++) {
            float s = 0.f;
#pragma unroll
            for (int nf = 0; nf < 4; nf++)
                s += fmaxf(acc[mf][nf][q] + br1v[nf], 0.f) * wr2v[nf];
#pragma unroll
            for (int off = 8; off >= 1; off >>= 1)
                s += __shfl_xor(s, off);
            if ((l & 15) == 0) {
                int row = m0 + wr * 64 + mf * 16 + (l >> 4) * 4 + q;
                pscore[(size_t)(blockIdx.y * 2 + wc) * M_ + row] = s;
            }
        }
}

// ---------------- exact top-k via 12-bit histogram select -----------------------
__global__ __launch_bounds__(1024) void topk_kernel(const float* __restrict__ pscore,
                                                    const float* __restrict__ br2,
                                                    int* __restrict__ sel_idx,
                                                    float* __restrict__ maskF) {
    __shared__ unsigned hist[4096];               // 16 KB (suffix-summed in place)
    __shared__ unsigned long long cand[4096];     // 32 KB
    __shared__ unsigned char flags[S_];           // 4 KB
    __shared__ unsigned cnts[2];                  // [0]=n_cand, [1]=sel slot
    __shared__ unsigned s_thr, s_above;
    int b = blockIdx.x, t = threadIdx.x;          // 1024 threads
    float bb = br2[0];

    for (int i = t; i < 4096; i += 1024) { hist[i] = 0; flags[i] = 0; }
    if (t < 2) cnts[t] = 0;
    __syncthreads();

    unsigned ureg[4];
#pragma unroll
    for (int r = 0; r < 4; r++) {
        int i = t + r * 1024;
        float f = bb;
#pragma unroll
        for (int s8 = 0; s8 < 8; s8++) f += pscore[(size_t)s8 * M_ + b * S_ + i];
        unsigned u = __float_as_uint(f);
        u = (u & 0x80000000u) ? ~u : (u | 0x80000000u);
        ureg[r] = u;
        atomicAdd(&hist[u >> 20], 1u);
    }
    __syncthreads();

    for (int d = 1; d < 4096; d <<= 1) {
        unsigned tmp[4];
#pragma unroll
        for (int r = 0; r < 4; r++) {
            int i = t + r * 1024;
            tmp[r] = (i + d < 4096) ? hist[i + d] : 0u;
        }
        __syncthreads();
#pragma unroll
        for (int r = 0; r < 4; r++) hist[t + r * 1024] += tmp[r];
        __syncthreads();
    }
#pragma unroll
    for (int r = 0; r < 4; r++) {
        int i = t + r * 1024;
        unsigned Si = hist[i];
        unsigned Sn = (i + 1 < 4096) ? hist[i + 1] : 0u;
        if (Si >= KSEL_ && Sn < KSEL_) { s_thr = (unsigned)i; s_above = Sn; }
    }
    __syncthreads();
    const unsigned thr = s_thr;
    const unsigned need = KSEL_ - s_above;

#pragma unroll
    for (int r = 0; r < 4; r++) {
        int i = t + r * 1024;
        unsigned u = ureg[r];
        unsigned bin = u >> 20;
        if (bin > thr) flags[i] = 1;
        else if (bin == thr) {
            unsigned slot = atomicAdd(&cnts[0], 1u);
            cand[slot] = ((unsigned long long)u << 32) | (unsigned)(S_ - 1 - i);
        }
    }
    __syncthreads();

    unsigned nc = cnts[0];
    unsigned ncp2 = 1; while (ncp2 < nc) ncp2 <<= 1;
    for (unsigned i = t + nc; i < ncp2; i += 1024) cand[i] = 0ull;
    __syncthreads();
    for (unsigned k = 2; k <= ncp2; k <<= 1)
        for (unsigned j = k >> 1; j > 0; j >>= 1) {
            for (unsigned i = t; i < ncp2; i += 1024) {
                unsigned li = i ^ j;
                if (li > i) {
                    unsigned long long a = cand[i], c = cand[li];
                    bool up = ((i & k) == 0);
                    if (up ? (a > c) : (a < c)) { cand[i] = c; cand[li] = a; }
                }
            }
            __syncthreads();
        }
    for (unsigned i = t; i < need; i += 1024) {
        unsigned long long kk = cand[ncp2 - need + i];
        flags[(S_ - 1) - (int)(kk & 0xFFFFFFFFu)] = 1;
    }
    __syncthreads();

#pragma unroll
    for (int r = 0; r < 4; r++) {
        int i = t + r * 1024;
        if (flags[i]) {
            unsigned slot = atomicAdd(&cnts[1], 1u);
            sel_idx[b * KSEL_ + slot] = i;
        }
        maskF[b * S_ + i] = flags[i] ? 1.0f : 0.0f;
    }
}

// ---------------- gather selected rows, convert to bf16 -------------------------
__global__ void gather_kernel(const float* __restrict__ x, const int* __restrict__ sel_idx,
                              unsigned short* __restrict__ sel) {
    int jrow = blockIdx.x;               // 0..2047
    int b = jrow >> 9;
    int tok = sel_idx[jrow];
    const float* src = x + ((size_t)(b * S_ + tok)) * D_;
    int t = threadIdx.x;                 // 256
    float4 v0 = ((const float4*)src)[2 * t];
    float4 v1 = ((const float4*)src)[2 * t + 1];
    unsigned p0 = (unsigned)f2bf(v0.x) | ((unsigned)f2bf(v0.y) << 16);
    unsigned p1 = (unsigned)f2bf(v0.z) | ((unsigned)f2bf(v0.w) << 16);
    unsigned p2 = (unsigned)f2bf(v1.x) | ((unsigned)f2bf(v1.y) << 16);
    unsigned p3 = (unsigned)f2bf(v1.z) | ((unsigned)f2bf(v1.w) << 16);
    *(uint4*)(sel + (size_t)jrow * D_ + t * 8) = make_uint4(p0, p1, p2, p3);
}

// ======== 256x256 8-wave pipelined bf16 GEMM, BK=64, dbuf LDS, counted vmcnt ====
#define STAGEAB(bufp, ktX) do {                                                   \
    const unsigned short* a_ = gA + (size_t)(ktX) * 64;                           \
    const unsigned short* b_ = gB + (size_t)(ktX) * 64;                           \
    char* la_ = (char*)(&lds[bufp][0][0]) + w * 1024;                             \
    char* lb_ = (char*)(&lds[bufp][1][0]) + w * 1024;                             \
    gload16(a_,                      la_);                                        \
    gload16(a_ +  64 * (size_t)K,    la_ + 8192);                                 \
    gload16(a_ + 128 * (size_t)K,    la_ + 16384);                                \
    gload16(a_ + 192 * (size_t)K,    la_ + 24576);                                \
    gload16(b_,                      lb_);                                        \
    gload16(b_ +  64 * (size_t)K,    lb_ + 8192);                                 \
    gload16(b_ + 128 * (size_t)K,    lb_ + 16384);                                \
    gload16(b_ + 192 * (size_t)K,    lb_ + 24576);                                \
  } while (0)

__global__ __launch_bounds__(512) void mfma_gemm256(const unsigned short* __restrict__ A,
                                                    const unsigned short* __restrict__ Bt,
                                                    int M, int N, int K, int kspan,
                                                    const float* __restrict__ bias,
                                                    unsigned short* __restrict__ Cbf,
                                                    unsigned short* __restrict__ partialB,
                                                    int epi) {
    __shared__ unsigned short lds[2][2][256 * 64];   // [buf][A|B][row*64 + elem]
    const int t = threadIdx.x;
    const int w = t >> 6, l = t & 63;
    const int m0 = blockIdx.y * 256, n0 = blockIdx.x * 256;
    const int wr = w >> 2, wc = w & 3;               // wave -> (2 x 4) C grid
    const int kbeg = blockIdx.z * kspan;
    const int NT = kspan / 64;

    f32x4 acc[8][4];
    const f32x4 zz = {0.f, 0.f, 0.f, 0.f};
#pragma unroll
    for (int m = 0; m < 8; m++)
#pragma unroll
        for (int n = 0; n < 4; n++) acc[m][n] = zz;

    const int srow = t >> 3;
    const int sch8 = (((t & 7) ^ ((t >> 3) & 7)) * 8);
    const unsigned short* gA = A + (size_t)(m0 + srow) * K + kbeg + sch8;
    const unsigned short* gB = Bt + (size_t)(n0 + srow) * K + kbeg + sch8;

    STAGEAB(0, 0);
    STAGEAB(1, 1);

    for (int kt = 0; kt < NT; ++kt) {
        if (kt + 1 < NT) { asm volatile("s_waitcnt vmcnt(8)" ::: "memory"); }
        else             { asm volatile("s_waitcnt vmcnt(0)" ::: "memory"); }
        __builtin_amdgcn_s_barrier();
        __builtin_amdgcn_sched_barrier(0);
        const int cur = kt & 1;
        const unsigned short* LA = &lds[cur][0][0];
        const unsigned short* LB = &lds[cur][1][0];
#pragma unroll
        for (int kk = 0; kk < 2; kk++) {
            const int sw_ = ((kk * 4 + (l >> 4)) ^ (l & 7)) * 8;
            bf16x8 bfr[4], af0[4], af1[4];
#pragma unroll
            for (int n = 0; n < 4; n++)
                bfr[n] = *(const bf16x8*)(LB + (wc * 64 + n * 16 + (l & 15)) * 64 + sw_);
#pragma unroll
            for (int m = 0; m < 4; m++) {
                af0[m] = *(const bf16x8*)(LA + (wr * 128 + m * 16 + (l & 15)) * 64 + sw_);
                af1[m] = *(const bf16x8*)(LA + (wr * 128 + 64 + m * 16 + (l & 15)) * 64 + sw_);
            }
            __builtin_amdgcn_s_setprio(1);
#pragma unroll
            for (int m = 0; m < 4; m++)
#pragma unroll
                for (int n = 0; n < 4; n++)
                    acc[m][n] = __builtin_amdgcn_mfma_f32_16x16x32_bf16(af0[m], bfr[n], acc[m][n], 0, 0, 0);
#pragma unroll
            for (int m = 0; m < 4; m++)
#pragma unroll
                for (int n = 0; n < 4; n++)
                    acc[4 + m][n] = __builtin_amdgcn_mfma_f32_16x16x32_bf16(af1[m], bfr[n], acc[4 + m][n], 0, 0, 0);
            __builtin_amdgcn_s_setprio(0);
        }
        __builtin_amdgcn_sched_barrier(0);
        __builtin_amdgcn_s_barrier();
        if (kt + 2 < NT) STAGEAB(cur, kt + 2);
    }

    if (epi == 0) {
#pragma unroll
        for (int m = 0; m < 8; m++) {
            int rowb = m0 + wr * 128 + m * 16 + (l >> 4) * 4;
#pragma unroll
            for (int n = 0; n < 4; n++) {
                int col = n0 + wc * 64 + n * 16 + (l & 15);
                float bv = bias[col];
#pragma unroll
                for (int q = 0; q < 4; q++) {
                    float v = fmaxf(acc[m][n][q] + bv, 0.f);
                    Cbf[(size_t)(rowb + q) * N + col] = f2bf(v);
                }
            }
        }
    } else {
        unsigned short* pseg = partialB + (size_t)blockIdx.z * M * N;
#pragma unroll
        for (int m = 0; m < 8; m++) {
            int rowb = m0 + wr * 128 + m * 16 + (l >> 4) * 4;
#pragma unroll
            for (int n = 0; n < 4; n++) {
                int col = n0 + wc * 64 + n * 16 + (l & 15);
#pragma unroll
                for (int q = 0; q < 4; q++)
                    pseg[(size_t)(rowb + q) * N + col] = f2bf(acc[m][n][q]);
            }
        }
    }
}

// ---------------- sum 4 split-K bf16 partials + bias, scatter to out rows -------
__global__ void reduce_scatter_kernel(const unsigned short* __restrict__ partial,
                                      const float* __restrict__ bias,
                                      const int* __restrict__ sel_idx,
                                      float* __restrict__ out) {
    int m = blockIdx.x;                  // 0..2047
    int t = threadIdx.x;                 // 256
    int brow = m >> 9;
    int tok = sel_idx[m];
    float* orow = out + ((size_t)(brow * S_ + tok)) * D_;
    int c = t * 8;
    const size_t seg = (size_t)MS_ * D_;
    const unsigned short* pb = partial + (size_t)m * D_ + c;
    float o[8];
#pragma unroll
    for (int j = 0; j < 8; j++) o[j] = bias[c + j];
#pragma unroll
    for (int s = 0; s < 4; s++) {
        uint4 v = *(const uint4*)(pb + s * seg);
        const unsigned short* e = (const unsigned short*)&v;
#pragma unroll
        for (int j = 0; j < 8; j++) o[j] += bf2f(e[j]);
    }
    *(float4*)(orow + c)     = *(float4*)&o[0];
    *(float4*)(orow + c + 4) = *(float4*)&o[4];
}

extern "C" void kernel_launch(void* const* d_in, const int* in_sizes, int n_in,
                              void* d_out, int out_size, void* d_ws, size_t ws_size,
                              hipStream_t stream) {
    const float* x   = (const float*)d_in[0];
    const float* Wr1 = (const float*)d_in[1];
    const float* br1 = (const float*)d_in[2];
    const float* Wr2 = (const float*)d_in[3];
    const float* br2 = (const float*)d_in[4];
    const float* Wf1 = (const float*)d_in[5];
    const float* bf1 = (const float*)d_in[6];
    const float* Wf2 = (const float*)d_in[7];
    const float* bf2 = (const float*)d_in[8];
    float* out = (float*)d_out;
    char* ws = (char*)d_ws;

    // ---- workspace layout (MiB offsets, phase-overlapped) ----
    unsigned short* xh    = (unsigned short*)(ws);
    unsigned short* xl    = (unsigned short*)(ws + (64u << 20));
    unsigned short* whiT  = (unsigned short*)(ws + (160u << 20));
    unsigned short* wloT  = (unsigned short*)(ws + (162u << 20));
    float* pscore         = (float*)(ws + (168u << 20));
    int* sel_idx          = (int*)(ws + (169u << 20));
    unsigned short* partB = (unsigned short*)(ws);               // 32MB bf16 partials
    unsigned short* w1t   = (unsigned short*)(ws + (64u << 20));
    unsigned short* w2t   = (unsigned short*)(ws + (96u << 20));
    unsigned short* h1    = (unsigned short*)(ws + (128u << 20));
    unsigned short* sel   = (unsigned short*)(ws + (160u << 20));
    float* maskF          = out + (size_t)B_ * S_ * D_;

    (void)in_sizes; (void)n_in; (void)out_size; (void)ws_size;

    // 1. split x into bf16 hi/lo (out-copy now fused in router)
    split_kernel<<<2048, 256, 0, stream>>>(x, xh, xl, (M_ * D_) / 8);
    // 2. Wr1 -> whiT / wloT
    wsplit_kernel<<<dim3(DQ_ / 32, D_ / 32), dim3(32, 8), 0, stream>>>(Wr1, whiT, wloT);
    // 3. pipelined router (3 products, 2 blocks/CU) + fused score + fused x->out copy
    router_mfma<<<dim3(M_ / 128, DQ_ / 128), 256, 0, stream>>>(
        xh, xl, whiT, wloT, br1, Wr2, pscore, x, out);
    // 4. exact top-k + mask (histogram select)
    topk_kernel<<<B_, 1024, 0, stream>>>(pscore, br2, sel_idx, maskF);
    // 5. gather selected tokens -> bf16
    gather_kernel<<<MS_, 256, 0, stream>>>(x, sel_idx, sel);
    // 6. FFN weight transpose + bf16 convert
    transpose_bf16_kernel<<<dim3(DF_ / 32, D_ / 32), dim3(32, 8), 0, stream>>>(Wf1, w1t, D_, DF_);
    transpose_bf16_kernel<<<dim3(D_ / 32, DF_ / 32), dim3(32, 8), 0, stream>>>(Wf2, w2t, DF_, D_);
    // 7. FFN gemm1: h1 = bf16(relu(sel @ Wf1 + bf1))   M=2048 N=8192 K=2048
    mfma_gemm256<<<dim3(DF_ / 256, MS_ / 256, 1), 512, 0, stream>>>(
        sel, w1t, MS_, DF_, D_, D_, bf1, h1, nullptr, 0);
    // 8. FFN gemm2, split-K=4 -> bf16 partials   M=2048 N=2048 K=8192
    mfma_gemm256<<<dim3(D_ / 256, MS_ / 256, 4), 512, 0, stream>>>(
        h1, w2t, MS_, D_, DF_, DF_ / 4, nullptr, nullptr, partB, 1);
    // 9. reduce bf16 partials + bias, scatter into out
    reduce_scatter_kernel<<<MS_, 256, 0, stream>>>(partB, bf2, sel_idx, out);
}

// Round 16
// 385.925 us; speedup vs baseline: 1.0997x; 1.0997x over previous
//
#include <hip/hip_runtime.h>

#define B_    4
#define S_    4096
#define D_    2048
#define DQ_   512
#define DF_   8192
#define KSEL_ 512
#define M_    (B_ * S_)     // 16384
#define MS_   (B_ * KSEL_)  // 2048 selected rows

typedef __attribute__((ext_vector_type(8))) short bf16x8;
typedef __attribute__((ext_vector_type(4))) float f32x4;
typedef __attribute__((address_space(3))) void as3_void;
typedef const __attribute__((address_space(1))) void as1_cvoid;

__device__ __forceinline__ unsigned short f2bf(float f) {
    unsigned u = __float_as_uint(f);
    u += 0x7FFFu + ((u >> 16) & 1u);   // RNE
    return (unsigned short)(u >> 16);
}
__device__ __forceinline__ float bf2f(unsigned short h) {
    return __uint_as_float(((unsigned)h) << 16);
}

__device__ __forceinline__ void gload16(const void* g, void* l) {
    __builtin_amdgcn_global_load_lds((as1_cvoid*)g, (as3_void*)l, 16, 0, 0);
}

// ---------------- split x into bf16 hi/lo AND copy x -> out ---------------------
__global__ void split_copy_kernel(const float* __restrict__ x,
                                  unsigned short* __restrict__ xh,
                                  unsigned short* __restrict__ xl,
                                  float* __restrict__ out, int n8) {
    int i = blockIdx.x * blockDim.x + threadIdx.x;
    int stride = gridDim.x * blockDim.x;
    for (; i < n8; i += stride) {
        float4 a = ((const float4*)x)[2 * i];
        float4 b = ((const float4*)x)[2 * i + 1];
        ((float4*)out)[2 * i]     = a;
        ((float4*)out)[2 * i + 1] = b;
        float v[8] = {a.x, a.y, a.z, a.w, b.x, b.y, b.z, b.w};
        unsigned short hi[8], lo[8];
#pragma unroll
        for (int j = 0; j < 8; j++) {
            hi[j] = f2bf(v[j]);
            lo[j] = f2bf(v[j] - bf2f(hi[j]));
        }
        *(uint4*)(xh + (size_t)i * 8) = *(const uint4*)hi;
        *(uint4*)(xl + (size_t)i * 8) = *(const uint4*)lo;
    }
}

// ---------------- Wr1 -> whiT [DQ][D], wloT [DQ][D] (bf16, transposed) ----------
__global__ void wsplit_kernel(const float* __restrict__ W,
                              unsigned short* __restrict__ whiT,
                              unsigned short* __restrict__ wloT) {
    __shared__ float tile[32][33];
    int tx = threadIdx.x, ty = threadIdx.y;          // 32 x 8
    int n0 = blockIdx.x * 32, k0 = blockIdx.y * 32;
#pragma unroll
    for (int j = 0; j < 4; j++)
        tile[ty + j * 8][tx] = W[(size_t)(k0 + ty + j * 8) * DQ_ + n0 + tx];   // tile[k][n]
    __syncthreads();
#pragma unroll
    for (int j = 0; j < 4; j++) {
        float v = tile[tx][ty + j * 8];              // k = k0+tx, n = n0+ty+j*8
        unsigned short hi = f2bf(v);
        unsigned short lo = f2bf(v - bf2f(hi));
        size_t row = (size_t)(n0 + ty + j * 8) * D_;
        whiT[row + k0 + tx] = hi;
        wloT[row + k0 + tx] = lo;
    }
}

// ---------------- transpose + fp32->bf16 convert: out[c][r] = bf16(in[r][c]) ----
__global__ void transpose_bf16_kernel(const float* __restrict__ in,
                                      unsigned short* __restrict__ out,
                                      int R, int C) {
    __shared__ float tile[32][33];
    int tx = threadIdx.x, ty = threadIdx.y;       // 32 x 8
    int c0 = blockIdx.x * 32, r0 = blockIdx.y * 32;
#pragma unroll
    for (int j = 0; j < 4; j++)
        tile[ty + j * 8][tx] = in[(size_t)(r0 + ty + j * 8) * C + c0 + tx];
    __syncthreads();
#pragma unroll
    for (int j = 0; j < 4; j++)
        out[(size_t)(c0 + ty + j * 8) * R + r0 + tx] = f2bf(tile[tx][ty + j * 8]);
}

// ======== pipelined router: 128x128 tile, BK=32, 4 waves, 2 blocks/CU ==========
// (R10 configuration — best measured: 112.8 us, MfmaUtil 39%, 0 conflicts)
#define RSTAGE(bufp, ktX) do {                                              \
    const size_t ko_ = (size_t)(ktX) * 32;                                  \
    char* laH_ = (char*)(&sA[bufp][0][0]) + w * 1024;                       \
    char* laL_ = (char*)(&sA[bufp][1][0]) + w * 1024;                       \
    char* lbH_ = (char*)(&sB[bufp][0][0]) + w * 1024;                       \
    char* lbL_ = (char*)(&sB[bufp][1][0]) + w * 1024;                       \
    gload16(gAh + ko_,            laH_);                                    \
    gload16(gAh + 64 * D_ + ko_,  laH_ + 4096);                             \
    gload16(gAl + ko_,            laL_);                                    \
    gload16(gAl + 64 * D_ + ko_,  laL_ + 4096);                             \
    gload16(gBh + ko_,            lbH_);                                    \
    gload16(gBh + 64 * D_ + ko_,  lbH_ + 4096);                             \
    gload16(gBl + ko_,            lbL_);                                    \
    gload16(gBl + 64 * D_ + ko_,  lbL_ + 4096);                             \
  } while (0)

__global__ __launch_bounds__(256) void router_mfma(const unsigned short* __restrict__ xh,
                                                   const unsigned short* __restrict__ xl,
                                                   const unsigned short* __restrict__ whiT,
                                                   const unsigned short* __restrict__ wloT,
                                                   const float* __restrict__ br1,
                                                   const float* __restrict__ Wr2,
                                                   float* __restrict__ pscore) {
    __shared__ unsigned short sA[2][2][128 * 32];   // [buf][hi|lo] 8KB tiles
    __shared__ unsigned short sB[2][2][128 * 32];
    const int t = threadIdx.x;
    const int w = t >> 6, l = t & 63;               // 4 waves
    const int m0 = blockIdx.x * 128, n0 = blockIdx.y * 128;
    const int wr = w >> 1, wc = w & 1;              // 2 x 2 wave grid, 64x64 each

    f32x4 acc[4][4];
    const f32x4 zz = {0.f, 0.f, 0.f, 0.f};
#pragma unroll
    for (int m = 0; m < 4; m++)
#pragma unroll
        for (int n = 0; n < 4; n++) acc[m][n] = zz;

    const int srow = t >> 2;
    const int sch8 = (((t & 3) ^ ((t >> 3) & 3)) * 8);
    const unsigned short* gAh = xh + (size_t)(m0 + srow) * D_ + sch8;
    const unsigned short* gAl = xl + (size_t)(m0 + srow) * D_ + sch8;
    const unsigned short* gBh = whiT + (size_t)(n0 + srow) * D_ + sch8;
    const unsigned short* gBl = wloT + (size_t)(n0 + srow) * D_ + sch8;

    RSTAGE(0, 0);
    RSTAGE(1, 1);

    const int fro = ((l >> 4) ^ ((l >> 1) & 3)) * 8;   // swizzled read chunk
    const int arB = (wr * 64 + (l & 15)) * 32 + fro;   // frag base (f adds 512)
    const int brB = (wc * 64 + (l & 15)) * 32 + fro;

    for (int kt = 0; kt < 64; ++kt) {
        if (kt + 1 < 64) { asm volatile("s_waitcnt vmcnt(8)" ::: "memory"); }
        else             { asm volatile("s_waitcnt vmcnt(0)" ::: "memory"); }
        __builtin_amdgcn_s_barrier();
        __builtin_amdgcn_sched_barrier(0);
        const int cur = kt & 1;
        const unsigned short* LAh = &sA[cur][0][0];
        const unsigned short* LAl = &sA[cur][1][0];
        const unsigned short* LBh = &sB[cur][0][0];
        const unsigned short* LBl = &sB[cur][1][0];
        bf16x8 ah[4], al[4], bh[4], bl[4];
#pragma unroll
        for (int f = 0; f < 4; f++) ah[f] = *(const bf16x8*)(LAh + arB + f * 512);
#pragma unroll
        for (int f = 0; f < 4; f++) bh[f] = *(const bf16x8*)(LBh + brB + f * 512);
#pragma unroll
        for (int f = 0; f < 4; f++) bl[f] = *(const bf16x8*)(LBl + brB + f * 512);
#pragma unroll
        for (int f = 0; f < 4; f++) al[f] = *(const bf16x8*)(LAl + arB + f * 512);
        __builtin_amdgcn_s_setprio(1);
#pragma unroll
        for (int m = 0; m < 4; m++)
#pragma unroll
            for (int n = 0; n < 4; n++)
                acc[m][n] = __builtin_amdgcn_mfma_f32_16x16x32_bf16(ah[m], bh[n], acc[m][n], 0, 0, 0);
#pragma unroll
        for (int m = 0; m < 4; m++)
#pragma unroll
            for (int n = 0; n < 4; n++)
                acc[m][n] = __builtin_amdgcn_mfma_f32_16x16x32_bf16(ah[m], bl[n], acc[m][n], 0, 0, 0);
#pragma unroll
        for (int m = 0; m < 4; m++)
#pragma unroll
            for (int n = 0; n < 4; n++)
                acc[m][n] = __builtin_amdgcn_mfma_f32_16x16x32_bf16(al[m], bh[n], acc[m][n], 0, 0, 0);
        __builtin_amdgcn_s_setprio(0);
        __builtin_amdgcn_sched_barrier(0);
        __builtin_amdgcn_s_barrier();
        if (kt + 2 < 64) RSTAGE(cur, kt + 2);
    }

    // epilogue: fused scores partial dot (relu(acc + br1) . Wr2 over 64-col slice)
    float br1v[4], wr2v[4];
#pragma unroll
    for (int nf = 0; nf < 4; nf++) {
        int col = n0 + wc * 64 + nf * 16 + (l & 15);
        br1v[nf] = br1[col];
        wr2v[nf] = Wr2[col];
    }
#pragma unroll
    for (int mf = 0; mf < 4; mf++)
#pragma unroll
        for (int q = 0; q < 4; q++) {
            float s = 0.f;
#pragma unroll
            for (int nf = 0; nf < 4; nf++)
                s += fmaxf(acc[mf][nf][q] + br1v[nf], 0.f) * wr2v[nf];
#pragma unroll
            for (int off = 8; off >= 1; off >>= 1)
                s += __shfl_xor(s, off);
            if ((l & 15) == 0) {
                int row = m0 + wr * 64 + mf * 16 + (l >> 4) * 4 + q;
                pscore[(size_t)(blockIdx.y * 2 + wc) * M_ + row] = s;
            }
        }
}

// ---------------- exact top-k via 12-bit histogram select -----------------------
__global__ __launch_bounds__(1024) void topk_kernel(const float* __restrict__ pscore,
                                                    const float* __restrict__ br2,
                                                    int* __restrict__ sel_idx,
                                                    float* __restrict__ maskF) {
    __shared__ unsigned hist[4096];               // 16 KB (suffix-summed in place)
    __shared__ unsigned long long cand[4096];     // 32 KB
    __shared__ unsigned char flags[S_];           // 4 KB
    __shared__ unsigned cnts[2];                  // [0]=n_cand, [1]=sel slot
    __shared__ unsigned s_thr, s_above;
    int b = blockIdx.x, t = threadIdx.x;          // 1024 threads
    float bb = br2[0];

    for (int i = t; i < 4096; i += 1024) { hist[i] = 0; flags[i] = 0; }
    if (t < 2) cnts[t] = 0;
    __syncthreads();

    unsigned ureg[4];
#pragma unroll
    for (int r = 0; r < 4; r++) {
        int i = t + r * 1024;
        float f = bb;
#pragma unroll
        for (int s8 = 0; s8 < 8; s8++) f += pscore[(size_t)s8 * M_ + b * S_ + i];
        unsigned u = __float_as_uint(f);
        u = (u & 0x80000000u) ? ~u : (u | 0x80000000u);
        ureg[r] = u;
        atomicAdd(&hist[u >> 20], 1u);
    }
    __syncthreads();

    for (int d = 1; d < 4096; d <<= 1) {
        unsigned tmp[4];
#pragma unroll
        for (int r = 0; r < 4; r++) {
            int i = t + r * 1024;
            tmp[r] = (i + d < 4096) ? hist[i + d] : 0u;
        }
        __syncthreads();
#pragma unroll
        for (int r = 0; r < 4; r++) hist[t + r * 1024] += tmp[r];
        __syncthreads();
    }
#pragma unroll
    for (int r = 0; r < 4; r++) {
        int i = t + r * 1024;
        unsigned Si = hist[i];
        unsigned Sn = (i + 1 < 4096) ? hist[i + 1] : 0u;
        if (Si >= KSEL_ && Sn < KSEL_) { s_thr = (unsigned)i; s_above = Sn; }
    }
    __syncthreads();
    const unsigned thr = s_thr;
    const unsigned need = KSEL_ - s_above;

#pragma unroll
    for (int r = 0; r < 4; r++) {
        int i = t + r * 1024;
        unsigned u = ureg[r];
        unsigned bin = u >> 20;
        if (bin > thr) flags[i] = 1;
        else if (bin == thr) {
            unsigned slot = atomicAdd(&cnts[0], 1u);
            cand[slot] = ((unsigned long long)u << 32) | (unsigned)(S_ - 1 - i);
        }
    }
    __syncthreads();

    unsigned nc = cnts[0];
    unsigned ncp2 = 1; while (ncp2 < nc) ncp2 <<= 1;
    for (unsigned i = t + nc; i < ncp2; i += 1024) cand[i] = 0ull;
    __syncthreads();
    for (unsigned k = 2; k <= ncp2; k <<= 1)
        for (unsigned j = k >> 1; j > 0; j >>= 1) {
            for (unsigned i = t; i < ncp2; i += 1024) {
                unsigned li = i ^ j;
                if (li > i) {
                    unsigned long long a = cand[i], c = cand[li];
                    bool up = ((i & k) == 0);
                    if (up ? (a > c) : (a < c)) { cand[i] = c; cand[li] = a; }
                }
            }
            __syncthreads();
        }
    for (unsigned i = t; i < need; i += 1024) {
        unsigned long long kk = cand[ncp2 - need + i];
        flags[(S_ - 1) - (int)(kk & 0xFFFFFFFFu)] = 1;
    }
    __syncthreads();

#pragma unroll
    for (int r = 0; r < 4; r++) {
        int i = t + r * 1024;
        if (flags[i]) {
            unsigned slot = atomicAdd(&cnts[1], 1u);
            sel_idx[b * KSEL_ + slot] = i;
        }
        maskF[b * S_ + i] = flags[i] ? 1.0f : 0.0f;
    }
}

// ---------------- gather selected rows, convert to bf16 -------------------------
__global__ void gather_kernel(const float* __restrict__ x, const int* __restrict__ sel_idx,
                              unsigned short* __restrict__ sel) {
    int jrow = blockIdx.x;               // 0..2047
    int b = jrow >> 9;
    int tok = sel_idx[jrow];
    const float* src = x + ((size_t)(b * S_ + tok)) * D_;
    int t = threadIdx.x;                 // 256
    float4 v0 = ((const float4*)src)[2 * t];
    float4 v1 = ((const float4*)src)[2 * t + 1];
    unsigned p0 = (unsigned)f2bf(v0.x) | ((unsigned)f2bf(v0.y) << 16);
    unsigned p1 = (unsigned)f2bf(v0.z) | ((unsigned)f2bf(v0.w) << 16);
    unsigned p2 = (unsigned)f2bf(v1.x) | ((unsigned)f2bf(v1.y) << 16);
    unsigned p3 = (unsigned)f2bf(v1.z) | ((unsigned)f2bf(v1.w) << 16);
    *(uint4*)(sel + (size_t)jrow * D_ + t * 8) = make_uint4(p0, p1, p2, p3);
}

// ======== 256x256 8-wave pipelined bf16 GEMM, BK=64, dbuf LDS, counted vmcnt ====
#define STAGEAB(bufp, ktX) do {                                                   \
    const unsigned short* a_ = gA + (size_t)(ktX) * 64;                           \
    const unsigned short* b_ = gB + (size_t)(ktX) * 64;                           \
    char* la_ = (char*)(&lds[bufp][0][0]) + w * 1024;                             \
    char* lb_ = (char*)(&lds[bufp][1][0]) + w * 1024;                             \
    gload16(a_,                      la_);                                        \
    gload16(a_ +  64 * (size_t)K,    la_ + 8192);                                 \
    gload16(a_ + 128 * (size_t)K,    la_ + 16384);                                \
    gload16(a_ + 192 * (size_t)K,    la_ + 24576);                                \
    gload16(b_,                      lb_);                                        \
    gload16(b_ +  64 * (size_t)K,    lb_ + 8192);                                 \
    gload16(b_ + 128 * (size_t)K,    lb_ + 16384);                                \
    gload16(b_ + 192 * (size_t)K,    lb_ + 24576);                                \
  } while (0)

__global__ __launch_bounds__(512) void mfma_gemm256(const unsigned short* __restrict__ A,
                                                    const unsigned short* __restrict__ Bt,
                                                    int M, int N, int K, int kspan,
                                                    const float* __restrict__ bias,
                                                    unsigned short* __restrict__ Cbf,
                                                    unsigned short* __restrict__ partialB,
                                                    int epi) {
    __shared__ unsigned short lds[2][2][256 * 64];   // [buf][A|B][row*64 + elem]
    const int t = threadIdx.x;
    const int w = t >> 6, l = t & 63;
    const int m0 = blockIdx.y * 256, n0 = blockIdx.x * 256;
    const int wr = w >> 2, wc = w & 3;               // wave -> (2 x 4) C grid
    const int kbeg = blockIdx.z * kspan;
    const int NT = kspan / 64;

    f32x4 acc[8][4];
    const f32x4 zz = {0.f, 0.f, 0.f, 0.f};
#pragma unroll
    for (int m = 0; m < 8; m++)
#pragma unroll
        for (int n = 0; n < 4; n++) acc[m][n] = zz;

    const int srow = t >> 3;
    const int sch8 = (((t & 7) ^ ((t >> 3) & 7)) * 8);
    const unsigned short* gA = A + (size_t)(m0 + srow) * K + kbeg + sch8;
    const unsigned short* gB = Bt + (size_t)(n0 + srow) * K + kbeg + sch8;

    STAGEAB(0, 0);
    STAGEAB(1, 1);

    for (int kt = 0; kt < NT; ++kt) {
        if (kt + 1 < NT) { asm volatile("s_waitcnt vmcnt(8)" ::: "memory"); }
        else             { asm volatile("s_waitcnt vmcnt(0)" ::: "memory"); }
        __builtin_amdgcn_s_barrier();
        __builtin_amdgcn_sched_barrier(0);
        const int cur = kt & 1;
        const unsigned short* LA = &lds[cur][0][0];
        const unsigned short* LB = &lds[cur][1][0];
#pragma unroll
        for (int kk = 0; kk < 2; kk++) {
            const int sw_ = ((kk * 4 + (l >> 4)) ^ (l & 7)) * 8;
            bf16x8 bfr[4], af0[4], af1[4];
#pragma unroll
            for (int n = 0; n < 4; n++)
                bfr[n] = *(const bf16x8*)(LB + (wc * 64 + n * 16 + (l & 15)) * 64 + sw_);
#pragma unroll
            for (int m = 0; m < 4; m++) {
                af0[m] = *(const bf16x8*)(LA + (wr * 128 + m * 16 + (l & 15)) * 64 + sw_);
                af1[m] = *(const bf16x8*)(LA + (wr * 128 + 64 + m * 16 + (l & 15)) * 64 + sw_);
            }
            __builtin_amdgcn_s_setprio(1);
#pragma unroll
            for (int m = 0; m < 4; m++)
#pragma unroll
                for (int n = 0; n < 4; n++)
                    acc[m][n] = __builtin_amdgcn_mfma_f32_16x16x32_bf16(af0[m], bfr[n], acc[m][n], 0, 0, 0);
#pragma unroll
            for (int m = 0; m < 4; m++)
#pragma unroll
                for (int n = 0; n < 4; n++)
                    acc[4 + m][n] = __builtin_amdgcn_mfma_f32_16x16x32_bf16(af1[m], bfr[n], acc[4 + m][n], 0, 0, 0);
            __builtin_amdgcn_s_setprio(0);
        }
        __builtin_amdgcn_sched_barrier(0);
        __builtin_amdgcn_s_barrier();
        if (kt + 2 < NT) STAGEAB(cur, kt + 2);
    }

    if (epi == 0) {
#pragma unroll
        for (int m = 0; m < 8; m++) {
            int rowb = m0 + wr * 128 + m * 16 + (l >> 4) * 4;
#pragma unroll
            for (int n = 0; n < 4; n++) {
                int col = n0 + wc * 64 + n * 16 + (l & 15);
                float bv = bias[col];
#pragma unroll
                for (int q = 0; q < 4; q++) {
                    float v = fmaxf(acc[m][n][q] + bv, 0.f);
                    Cbf[(size_t)(rowb + q) * N + col] = f2bf(v);
                }
            }
        }
    } else {
        unsigned short* pseg = partialB + (size_t)blockIdx.z * M * N;
#pragma unroll
        for (int m = 0; m < 8; m++) {
            int rowb = m0 + wr * 128 + m * 16 + (l >> 4) * 4;
#pragma unroll
            for (int n = 0; n < 4; n++) {
                int col = n0 + wc * 64 + n * 16 + (l & 15);
#pragma unroll
                for (int q = 0; q < 4; q++)
                    pseg[(size_t)(rowb + q) * N + col] = f2bf(acc[m][n][q]);
            }
        }
    }
}

// ---------------- sum 4 split-K bf16 partials + bias, scatter to out rows -------
__global__ void reduce_scatter_kernel(const unsigned short* __restrict__ partial,
                                      const float* __restrict__ bias,
                                      const int* __restrict__ sel_idx,
                                      float* __restrict__ out) {
    int m = blockIdx.x;                  // 0..2047
    int t = threadIdx.x;                 // 256
    int brow = m >> 9;
    int tok = sel_idx[m];
    float* orow = out + ((size_t)(brow * S_ + tok)) * D_;
    int c = t * 8;
    const size_t seg = (size_t)MS_ * D_;
    const unsigned short* pb = partial + (size_t)m * D_ + c;
    float o[8];
#pragma unroll
    for (int j = 0; j < 8; j++) o[j] = bias[c + j];
#pragma unroll
    for (int s = 0; s < 4; s++) {
        uint4 v = *(const uint4*)(pb + s * seg);
        const unsigned short* e = (const unsigned short*)&v;
#pragma unroll
        for (int j = 0; j < 8; j++) o[j] += bf2f(e[j]);
    }
    *(float4*)(orow + c)     = *(float4*)&o[0];
    *(float4*)(orow + c + 4) = *(float4*)&o[4];
}

extern "C" void kernel_launch(void* const* d_in, const int* in_sizes, int n_in,
                              void* d_out, int out_size, void* d_ws, size_t ws_size,
                              hipStream_t stream) {
    const float* x   = (const float*)d_in[0];
    const float* Wr1 = (const float*)d_in[1];
    const float* br1 = (const float*)d_in[2];
    const float* Wr2 = (const float*)d_in[3];
    const float* br2 = (const float*)d_in[4];
    const float* Wf1 = (const float*)d_in[5];
    const float* bf1 = (const float*)d_in[6];
    const float* Wf2 = (const float*)d_in[7];
    const float* bf2 = (const float*)d_in[8];
    float* out = (float*)d_out;
    char* ws = (char*)d_ws;

    // ---- workspace layout (MiB offsets, phase-overlapped) ----
    unsigned short* xh    = (unsigned short*)(ws);
    unsigned short* xl    = (unsigned short*)(ws + (64u << 20));
    unsigned short* whiT  = (unsigned short*)(ws + (160u << 20));
    unsigned short* wloT  = (unsigned short*)(ws + (162u << 20));
    float* pscore         = (float*)(ws + (168u << 20));
    int* sel_idx          = (int*)(ws + (169u << 20));
    unsigned short* partB = (unsigned short*)(ws);               // 32MB bf16 partials
    unsigned short* w1t   = (unsigned short*)(ws + (64u << 20));
    unsigned short* w2t   = (unsigned short*)(ws + (96u << 20));
    unsigned short* h1    = (unsigned short*)(ws + (128u << 20));
    unsigned short* sel   = (unsigned short*)(ws + (160u << 20));
    float* maskF          = out + (size_t)B_ * S_ * D_;

    (void)in_sizes; (void)n_in; (void)out_size; (void)ws_size;

    // 1. split x into bf16 hi/lo + copy x -> out
    split_copy_kernel<<<2048, 256, 0, stream>>>(x, xh, xl, out, (M_ * D_) / 8);
    // 2. Wr1 -> whiT / wloT
    wsplit_kernel<<<dim3(DQ_ / 32, D_ / 32), dim3(32, 8), 0, stream>>>(Wr1, whiT, wloT);
    // 3. pipelined router (3 products, 2 blocks/CU) + fused score
    router_mfma<<<dim3(M_ / 128, DQ_ / 128), 256, 0, stream>>>(
        xh, xl, whiT, wloT, br1, Wr2, pscore);
    // 4. exact top-k + mask (histogram select)
    topk_kernel<<<B_, 1024, 0, stream>>>(pscore, br2, sel_idx, maskF);
    // 5. gather selected tokens -> bf16
    gather_kernel<<<MS_, 256, 0, stream>>>(x, sel_idx, sel);
    // 6. FFN weight transpose + bf16 convert
    transpose_bf16_kernel<<<dim3(DF_ / 32, D_ / 32), dim3(32, 8), 0, stream>>>(Wf1, w1t, D_, DF_);
    transpose_bf16_kernel<<<dim3(D_ / 32, DF_ / 32), dim3(32, 8), 0, stream>>>(Wf2, w2t, DF_, D_);
    // 7. FFN gemm1: h1 = bf16(relu(sel @ Wf1 + bf1))   M=2048 N=8192 K=2048
    mfma_gemm256<<<dim3(DF_ / 256, MS_ / 256, 1), 512, 0, stream>>>(
        sel, w1t, MS_, DF_, D_, D_, bf1, h1, nullptr, 0);
    // 8. FFN gemm2, split-K=4 -> bf16 partials   M=2048 N=2048 K=8192
    mfma_gemm256<<<dim3(D_ / 256, MS_ / 256, 4), 512, 0, stream>>>(
        h1, w2t, MS_, D_, DF_, DF_ / 4, nullptr, nullptr, partB, 1);
    // 9. reduce bf16 partials + bias, scatter into out
    reduce_scatter_kernel<<<MS_, 256, 0, stream>>>(partB, bf2, sel_idx, out);
}